// Round 1
// baseline (1272.115 us; speedup 1.0000x reference)
//
#include <hip/hip_runtime.h>
#include <stdint.h>
#include <math.h>

// ---------------------------------------------------------------------------
// MPCN (B=128, R=30, L=60, D=300, V=50000, P=3), f32 end-to-end.
// Key risk: reproducing JAX threefry-partitionable gumbel bits exactly.
// ---------------------------------------------------------------------------

__host__ __device__ static inline void tf2x32(uint32_t k0, uint32_t k1,
                                              uint32_t x0, uint32_t x1,
                                              uint32_t* o0, uint32_t* o1) {
  uint32_t ks[3] = {k0, k1, k0 ^ k1 ^ 0x1BD11BDAu};
  x0 += ks[0]; x1 += ks[1];
  const int rotA[4] = {13, 15, 26, 6};
  const int rotB[4] = {17, 29, 16, 24};
#pragma unroll
  for (int i = 0; i < 5; ++i) {
    const int* rot = ((i & 1) == 0) ? rotA : rotB;
#pragma unroll
    for (int j = 0; j < 4; ++j) {
      x0 += x1;
      x1 = (x1 << rot[j]) | (x1 >> (32 - rot[j]));
      x1 ^= x0;
    }
    x0 += ks[(i + 1) % 3];
    x1 += ks[(i + 2) % 3] + (uint32_t)(i + 1);
  }
  *o0 = x0; *o1 = x1;
}

// JAX partitionable 32-bit draw: bits = o0 ^ o1 of threefry(key, (0, flat_idx))
__device__ static inline float jax_gumbel32(uint32_t k0, uint32_t k1, uint32_t idx) {
  uint32_t o0, o1;
  tf2x32(k0, k1, 0u, idx, &o0, &o1);
  uint32_t bits = o0 ^ o1;
  float f = __uint_as_float((bits >> 9) | 0x3f800000u) - 1.0f;
  float u = (f > 0.0f) ? f : 1.17549435e-38f;  // minval = f32 tiny
  return -logf(-logf(u));
}

// K1: per-(side,b,r) sum of token embeddings over L -> S[(side*3840+row)*300+d]
__global__ __launch_bounds__(320)
void gather_sum_kernel(const int* __restrict__ uRevs, const int* __restrict__ iRevs,
                       const float* __restrict__ uEmb, const float* __restrict__ iEmb,
                       float* __restrict__ S) {
  int bid = blockIdx.x;            // 0..7679
  int side = bid / 3840;
  int row = bid - side * 3840;
  const int* revs = side ? iRevs : uRevs;
  const float* emb = side ? iEmb : uEmb;
  __shared__ int toks[60];
  int t = threadIdx.x;
  if (t < 60) toks[t] = revs[row * 60 + t];
  __syncthreads();
  if (t < 300) {
    float acc = 0.f;
    for (int l = 0; l < 60; ++l)
      acc += emb[(size_t)toks[l] * 300 + t];
    S[(size_t)bid * 300 + t] = acc;
  }
}

// Tiled f32 "linear": Y[N,300] = X[N,300] @ W(.T) (+bias).
// TRANS: Y[n,d] = sum_k X[n,k]*W[d,k]   (W row-major [300,300])
// !TRANS: Y[n,e] = sum_k X[n,k]*W[k,e]
// BM=BN=64, BK=20, 256 threads, 4x4 micro-tile. N must be a multiple of 64.
template <bool TRANS, bool BIAS>
__global__ __launch_bounds__(256)
void linear_kernel(const float* __restrict__ X, const float* __restrict__ W,
                   const float* __restrict__ bias, float* __restrict__ Y, int N) {
  __shared__ __align__(16) float Xs[20][64];
  __shared__ __align__(16) float Ws_[20][64];
  int t = threadIdx.x;
  int bm = blockIdx.x * 64;
  int n0 = blockIdx.y * 64;
  int tm4 = (t >> 4) * 4;
  int tn4 = (t & 15) * 4;
  float acc[4][4] = {{0.f}};
  int xm = t >> 2;            // 0..63
  int xk = (t & 3) * 5;       // 0,5,10,15
  for (int k0 = 0; k0 < 300; k0 += 20) {
    const float* xp = X + (size_t)(bm + xm) * 300 + k0 + xk;
#pragma unroll
    for (int j = 0; j < 5; ++j) Xs[xk + j][xm] = xp[j];
    if (TRANS) {
      int dIdx = n0 + xm;
      bool ok = dIdx < 300;
      const float* wp = W + (size_t)dIdx * 300 + k0 + xk;
#pragma unroll
      for (int j = 0; j < 5; ++j) Ws_[xk + j][xm] = ok ? wp[j] : 0.f;
    } else {
#pragma unroll
      for (int i = 0; i < 5; ++i) {
        int flat = t + i * 256;       // 0..1279
        int kk = flat >> 6;
        int nn = flat & 63;
        int col = n0 + nn;
        Ws_[kk][nn] = (col < 300) ? W[(size_t)(k0 + kk) * 300 + col] : 0.f;
      }
    }
    __syncthreads();
#pragma unroll
    for (int kk = 0; kk < 20; ++kk) {
      const float4 a = *(const float4*)&Xs[kk][tm4];
      const float4 w = *(const float4*)&Ws_[kk][tn4];
      float av[4] = {a.x, a.y, a.z, a.w};
      float wv[4] = {w.x, w.y, w.z, w.w};
#pragma unroll
      for (int i = 0; i < 4; ++i)
#pragma unroll
        for (int j = 0; j < 4; ++j)
          acc[i][j] = fmaf(av[i], wv[j], acc[i][j]);
    }
    __syncthreads();
  }
  float bv[4] = {0.f, 0.f, 0.f, 0.f};
  if (BIAS) {
#pragma unroll
    for (int j = 0; j < 4; ++j) {
      int col = n0 + tn4 + j;
      if (col < 300) bv[j] = bias[col];
    }
  }
#pragma unroll
  for (int i = 0; i < 4; ++i) {
    int row = bm + tm4 + i;
    float* yp = Y + (size_t)row * 300 + n0 + tn4;
#pragma unroll
    for (int j = 0; j < 4; ++j) {
      int col = n0 + tn4 + j;
      if (col < 300) yp[j] = acc[i][j] + bv[j];
    }
  }
}

__global__ __launch_bounds__(256)
void gate_combine_kernel(const float* __restrict__ A, const float* __restrict__ Bv,
                         float* __restrict__ Y, int n) {
  int i = blockIdx.x * 256 + threadIdx.x;
  if (i < n) {
    float a = A[i], b = Bv[i];
    Y[i] = (1.f / (1.f + expf(-a))) * tanhf(b);
  }
}

// Review-level scores S[r,s]=dot(T[b,r],I[b,s]); max-pool both axes; +gumbel; argmax.
__global__ __launch_bounds__(256)
void review_argmax_kernel(const float* __restrict__ T, const float* __restrict__ I,
                          int* __restrict__ idxU, int* __restrict__ idxI,
                          uint32_t ku0, uint32_t ku1, uint32_t ki0, uint32_t ki1) {
  int b = blockIdx.x, t = threadIdx.x;
  __shared__ float Is[9000];   // 36 KB
  __shared__ float Sc[900];
  __shared__ float us[30], vs[30];
  const float* Tb = T + (size_t)b * 9000;
  const float* Ib = I + (size_t)b * 9000;
  for (int e = t; e < 9000; e += 256) Is[e] = Ib[e];
  __syncthreads();
  for (int id = t; id < 900; id += 256) {
    int r = id / 30, c = id - r * 30;
    const float* tr = Tb + r * 300;
    const float* ic = Is + c * 300;
    float acc = 0.f;
    for (int k = 0; k < 300; ++k) acc = fmaf(tr[k], ic[k], acc);
    Sc[id] = acc;
  }
  __syncthreads();
  if (t < 30) {
    float m = -3.4e38f;
    for (int c = 0; c < 30; ++c) m = fmaxf(m, Sc[t * 30 + c]);
    us[t] = m + jax_gumbel32(ku0, ku1, (uint32_t)(b * 30 + t));
  } else if (t >= 64 && t < 94) {
    int s = t - 64;
    float m = -3.4e38f;
    for (int r = 0; r < 30; ++r) m = fmaxf(m, Sc[r * 30 + s]);
    vs[s] = m + jax_gumbel32(ki0, ki1, (uint32_t)(b * 30 + s));
  }
  __syncthreads();
  if (t == 0) {
    int best = 0; float bvv = us[0];
    for (int r = 1; r < 30; ++r) { if (us[r] > bvv) { bvv = us[r]; best = r; } }
    idxU[b] = best;
  } else if (t == 1) {
    int best = 0; float bvv = vs[0];
    for (int s = 1; s < 30; ++s) { if (vs[s] > bvv) { bvv = vs[s]; best = s; } }
    idxI[b] = best;
  }
}

// Gather selected review's word embeddings -> WRD rows (user: 0..7679, item: 7680..)
__global__ __launch_bounds__(256)
void gather_words_kernel(const int* __restrict__ uRevs, const int* __restrict__ iRevs,
                         const float* __restrict__ uEmb, const float* __restrict__ iEmb,
                         const int* __restrict__ idxU, const int* __restrict__ idxI,
                         float* __restrict__ WRD) {
  int bid = blockIdx.x;  // 0..255
  int side = bid / 128;
  int b = bid - side * 128;
  const int* revs = side ? iRevs : uRevs;
  const float* emb = side ? iEmb : uEmb;
  int idx = side ? idxI[b] : idxU[b];
  __shared__ int toks[60];
  int t = threadIdx.x;
  if (t < 60) toks[t] = revs[(b * 30 + idx) * 60 + t];
  __syncthreads();
  float* dst = WRD + ((size_t)side * 7680 + (size_t)b * 60) * 300;
  for (int e = t; e < 18000; e += 256) {
    int l = e / 300;
    dst[e] = emb[(size_t)toks[l] * 300 + (e - l * 300)];
  }
}

// Word-level: S2[lu,li]=dot(TW[b,lu],IW[b,li]); row/col means; softmax; weighted sums.
__global__ __launch_bounds__(256)
void word_attend_kernel(const float* __restrict__ TW, const float* __restrict__ IW,
                        const float* __restrict__ WRDu, const float* __restrict__ WRDi,
                        float* __restrict__ JNT, int p) {
  int b = blockIdx.x, t = threadIdx.x;
  __shared__ float S2[3600];   // 14.4 KB
  __shared__ float pu[60], pi[60];
  const float* TWb = TW + (size_t)b * 18000;
  const float* IWb = IW + (size_t)b * 18000;
  for (int g = t; g < 900; g += 256) {       // each computes 4 li for one lu
    int lu = g / 15;
    int li0 = (g - lu * 15) * 4;
    const float* twr = TWb + lu * 300;
    const float* i0 = IWb + li0 * 300;
    float a0 = 0.f, a1 = 0.f, a2 = 0.f, a3 = 0.f;
    for (int k = 0; k < 300; ++k) {
      float tv = twr[k];
      a0 = fmaf(tv, i0[k], a0);
      a1 = fmaf(tv, i0[300 + k], a1);
      a2 = fmaf(tv, i0[600 + k], a2);
      a3 = fmaf(tv, i0[900 + k], a3);
    }
    float* s = S2 + lu * 60 + li0;
    s[0] = a0; s[1] = a1; s[2] = a2; s[3] = a3;
  }
  __syncthreads();
  if (t < 60) {
    float sacc = 0.f;
    for (int li = 0; li < 60; ++li) sacc += S2[t * 60 + li];
    pu[t] = sacc / 60.f;
  } else if (t >= 64 && t < 124) {
    int li = t - 64;
    float sacc = 0.f;
    for (int lu = 0; lu < 60; ++lu) sacc += S2[lu * 60 + li];
    pi[li] = sacc / 60.f;
  }
  __syncthreads();
  if (t == 0) {
    float m = -3.4e38f;
    for (int l = 0; l < 60; ++l) m = fmaxf(m, pu[l]);
    float ssum = 0.f;
    for (int l = 0; l < 60; ++l) { float e = expf(pu[l] - m); pu[l] = e; ssum += e; }
    float inv = 1.f / ssum;
    for (int l = 0; l < 60; ++l) pu[l] *= inv;
  } else if (t == 1) {
    float m = -3.4e38f;
    for (int l = 0; l < 60; ++l) m = fmaxf(m, pi[l]);
    float ssum = 0.f;
    for (int l = 0; l < 60; ++l) { float e = expf(pi[l] - m); pi[l] = e; ssum += e; }
    float inv = 1.f / ssum;
    for (int l = 0; l < 60; ++l) pi[l] *= inv;
  }
  __syncthreads();
  const float* WU = WRDu + (size_t)b * 18000;
  const float* WI = WRDi + (size_t)b * 18000;
  float* ju = JNT + (size_t)b * 1800 + p * 300;
  float* ji = ju + 900;
  for (int d = t; d < 300; d += 256) {
    float au = 0.f, ai = 0.f;
    for (int l = 0; l < 60; ++l) {
      au = fmaf(pu[l], WU[l * 300 + d], au);
      ai = fmaf(pi[l], WI[l * 300 + d], ai);
    }
    ju[d] = au;
    ji[d] = ai;
  }
}

// Factorization machine: out[b] = w0 + <fw, x> + 0.5*sum_k[(x@v)_k^2 - (x^2@v^2)_k]
__global__ __launch_bounds__(64)
void fm_kernel(const float* __restrict__ JNT, const float* __restrict__ w0,
               const float* __restrict__ fw, const float* __restrict__ fv,
               float* __restrict__ out) {
  int b = blockIdx.x, lane = threadIdx.x;
  const float* x = JNT + (size_t)b * 1800;
  float lin = 0.f;
  float t1[10], t2[10];
#pragma unroll
  for (int k = 0; k < 10; ++k) { t1[k] = 0.f; t2[k] = 0.f; }
  for (int j = lane; j < 1800; j += 64) {
    float xv = x[j];
    lin = fmaf(fw[j], xv, lin);
    float xx = xv * xv;
#pragma unroll
    for (int k = 0; k < 10; ++k) {
      float v = fv[j * 10 + k];
      t1[k] = fmaf(xv, v, t1[k]);
      t2[k] = fmaf(xx, v * v, t2[k]);
    }
  }
#pragma unroll
  for (int m = 32; m >= 1; m >>= 1) {
    lin += __shfl_xor(lin, m);
#pragma unroll
    for (int k = 0; k < 10; ++k) {
      t1[k] += __shfl_xor(t1[k], m);
      t2[k] += __shfl_xor(t2[k], m);
    }
  }
  if (lane == 0) {
    float inter = 0.f;
#pragma unroll
    for (int k = 0; k < 10; ++k) inter += t1[k] * t1[k] - t2[k];
    out[b] = w0[0] + lin + 0.5f * inter;
  }
}

extern "C" void kernel_launch(void* const* d_in, const int* in_sizes, int n_in,
                              void* d_out, int out_size, void* d_ws, size_t ws_size,
                              hipStream_t stream) {
  (void)in_sizes; (void)n_in; (void)out_size;
  const int*   uRevs = (const int*)d_in[0];
  const int*   iRevs = (const int*)d_in[1];
  const float* uEmb  = (const float*)d_in[2];
  const float* iEmb  = (const float*)d_in[3];
  const float* g1w   = (const float*)d_in[4];
  const float* g1b   = (const float*)d_in[5];
  const float* g2w   = (const float*)d_in[6];
  const float* g2b   = (const float*)d_in[7];
  const float* Mr    = (const float*)d_in[8];
  const float* Wur   = (const float*)d_in[9];
  const float* bur   = (const float*)d_in[10];
  const float* Wir   = (const float*)d_in[11];
  const float* bir   = (const float*)d_in[12];
  const float* Mw    = (const float*)d_in[13];
  const float* Wuw   = (const float*)d_in[14];
  const float* buw   = (const float*)d_in[15];
  const float* Wiw   = (const float*)d_in[16];
  const float* biw   = (const float*)d_in[17];
  const float* fmw0  = (const float*)d_in[18];
  const float* fmw   = (const float*)d_in[19];
  const float* fmv   = (const float*)d_in[20];
  float* out = (float*)d_out;

  float* ws = (float*)d_ws;
  // Arena (floats). Phase reuse: gate {S,G1,G2}->REV; review {UP,IP,TP}+REV;
  // word {WRD,UW,IW2,TW}->JNT; idx at top.
  const size_t NEED_BYTES = (size_t)(11750400 + 768) * 4;
  if (ws_size < NEED_BYTES) return;  // fail-safe: insufficient scratch

  float* S   = ws + 0;         // 7680*300
  float* G1  = ws + 2304000;
  float* G2  = ws + 4608000;
  float* REV = ws + 6912000;   // 7680*300 (user rows 0.., item rows 3840..)
  float* UP  = ws + 0;         // 3840*300
  float* IPb = ws + 1152000;
  float* TP  = ws + 2304000;
  float* WRD = ws + 0;         // 15360*300 (user 0.., item 7680..)
  float* UW  = ws + 4608000;   // 7680*300
  float* IW2 = ws + 6912000;
  float* TW  = ws + 9216000;
  float* JNT = ws + 11520000;  // 128*1800
  int*   idxU = (int*)(ws + 11750400);  // P*B = 384
  int*   idxI = idxU + 384;

  // Phase 1: gather-sum + review gate
  gather_sum_kernel<<<dim3(7680), dim3(320), 0, stream>>>(uRevs, iRevs, uEmb, iEmb, S);
  {
    dim3 g(7680 / 64, 5);
    linear_kernel<true, true><<<g, 256, 0, stream>>>(S, g1w, g1b, G1, 7680);
    linear_kernel<true, true><<<g, 256, 0, stream>>>(S, g2w, g2b, G2, 7680);
  }
  gate_combine_kernel<<<dim3(9000), 256, 0, stream>>>(G1, G2, REV, 2304000);

  // Phase 2: review-level co-attention + gumbel-argmax selection (all p)
  for (int p = 0; p < 3; ++p) {
    dim3 g(3840 / 64, 5);
    linear_kernel<true, true><<<g, 256, 0, stream>>>(
        REV, Wur + (size_t)p * 90000, bur + p * 300, UP, 3840);
    linear_kernel<true, true><<<g, 256, 0, stream>>>(
        REV + (size_t)3840 * 300, Wir + (size_t)p * 90000, bir + p * 300, IPb, 3840);
    linear_kernel<false, false><<<g, 256, 0, stream>>>(
        UP, Mr + (size_t)p * 90000, nullptr, TP, 3840);
    uint32_t ku0, ku1, ki0, ki1;  // fold_in(key(42), 2p) / (2p+1), host-side threefry
    tf2x32(0u, 42u, 0u, (uint32_t)(2 * p), &ku0, &ku1);
    tf2x32(0u, 42u, 0u, (uint32_t)(2 * p + 1), &ki0, &ki1);
    review_argmax_kernel<<<dim3(128), 256, 0, stream>>>(
        TP, IPb, idxU + p * 128, idxI + p * 128, ku0, ku1, ki0, ki1);
  }

  // Phase 3: word-level co-attention per p -> JNT columns
  for (int p = 0; p < 3; ++p) {
    gather_words_kernel<<<dim3(256), 256, 0, stream>>>(
        uRevs, iRevs, uEmb, iEmb, idxU + p * 128, idxI + p * 128, WRD);
    dim3 g(7680 / 64, 5);
    linear_kernel<true, true><<<g, 256, 0, stream>>>(
        WRD, Wuw + (size_t)p * 90000, buw + p * 300, UW, 7680);
    linear_kernel<true, true><<<g, 256, 0, stream>>>(
        WRD + (size_t)7680 * 300, Wiw + (size_t)p * 90000, biw + p * 300, IW2, 7680);
    linear_kernel<false, false><<<g, 256, 0, stream>>>(
        UW, Mw + (size_t)p * 90000, nullptr, TW, 7680);
    word_attend_kernel<<<dim3(128), 256, 0, stream>>>(
        TW, IW2, WRD, WRD + (size_t)7680 * 300, JNT, p);
  }

  // Phase 4: factorization machine
  fm_kernel<<<dim3(128), 64, 0, stream>>>(JNT, fmw0, fmw, fmv, out);
}

// Round 2
// 440.189 us; speedup vs baseline: 2.8899x; 2.8899x over previous
//
#include <hip/hip_runtime.h>
#include <stdint.h>
#include <math.h>

// ---------------------------------------------------------------------------
// MPCN (B=128, R=30, L=60, D=300, V=50000, P=3), f32 end-to-end.
// Round 2: word-level co-attention factorized through the mean (soft path),
// review-level kept bitwise-identical to round 1 (argmax selections frozen).
// ---------------------------------------------------------------------------

__host__ __device__ static inline void tf2x32(uint32_t k0, uint32_t k1,
                                              uint32_t x0, uint32_t x1,
                                              uint32_t* o0, uint32_t* o1) {
  uint32_t ks[3] = {k0, k1, k0 ^ k1 ^ 0x1BD11BDAu};
  x0 += ks[0]; x1 += ks[1];
  const int rotA[4] = {13, 15, 26, 6};
  const int rotB[4] = {17, 29, 16, 24};
#pragma unroll
  for (int i = 0; i < 5; ++i) {
    const int* rot = ((i & 1) == 0) ? rotA : rotB;
#pragma unroll
    for (int j = 0; j < 4; ++j) {
      x0 += x1;
      x1 = (x1 << rot[j]) | (x1 >> (32 - rot[j]));
      x1 ^= x0;
    }
    x0 += ks[(i + 1) % 3];
    x1 += ks[(i + 2) % 3] + (uint32_t)(i + 1);
  }
  *o0 = x0; *o1 = x1;
}

struct GKeys { uint32_t v[12]; };

// JAX partitionable 32-bit draw: bits = o0 ^ o1 of threefry(key, (0, flat_idx))
__device__ static inline float jax_gumbel32(uint32_t k0, uint32_t k1, uint32_t idx) {
  uint32_t o0, o1;
  tf2x32(k0, k1, 0u, idx, &o0, &o1);
  uint32_t bits = o0 ^ o1;
  float f = __uint_as_float((bits >> 9) | 0x3f800000u) - 1.0f;
  float u = (f > 0.0f) ? f : 1.17549435e-38f;  // minval = f32 tiny
  return -logf(-logf(u));
}

// K1: per-(side,b,r) sum of token embeddings over L -> S[(side*3840+row)*300+d]
__global__ __launch_bounds__(320)
void gather_sum_kernel(const int* __restrict__ uRevs, const int* __restrict__ iRevs,
                       const float* __restrict__ uEmb, const float* __restrict__ iEmb,
                       float* __restrict__ S) {
  int bid = blockIdx.x;            // 0..7679
  int side = bid / 3840;
  int row = bid - side * 3840;
  const int* revs = side ? iRevs : uRevs;
  const float* emb = side ? iEmb : uEmb;
  __shared__ int toks[60];
  int t = threadIdx.x;
  if (t < 60) toks[t] = revs[row * 60 + t];
  __syncthreads();
  if (t < 300) {
    float acc = 0.f;
    for (int l = 0; l < 60; ++l)
      acc += emb[(size_t)toks[l] * 300 + t];
    S[(size_t)bid * 300 + t] = acc;
  }
}

// Fused review gate: REV[n,d] = sigmoid(S@g1w^T+g1b) * tanh(S@g2w^T+g2b)
// Same tiling and per-accumulator FMA order as round-1 linear_kernel -> REV
// is bitwise identical to the round-1 two-launch + combine path.
__global__ __launch_bounds__(256)
void gate_fused_kernel(const float* __restrict__ X,
                       const float* __restrict__ W1, const float* __restrict__ b1,
                       const float* __restrict__ W2, const float* __restrict__ b2,
                       float* __restrict__ Y) {
  __shared__ __align__(16) float Xs[20][64];
  __shared__ __align__(16) float Ws1[20][64];
  __shared__ __align__(16) float Ws2[20][64];
  int t = threadIdx.x;
  int bm = blockIdx.x * 64;
  int n0 = blockIdx.y * 64;
  int tm4 = (t >> 4) * 4;
  int tn4 = (t & 15) * 4;
  float acc1[4][4] = {{0.f}};
  float acc2[4][4] = {{0.f}};
  int xm = t >> 2;
  int xk = (t & 3) * 5;
  for (int k0 = 0; k0 < 300; k0 += 20) {
    const float* xp = X + (size_t)(bm + xm) * 300 + k0 + xk;
#pragma unroll
    for (int j = 0; j < 5; ++j) Xs[xk + j][xm] = xp[j];
    {
      int dIdx = n0 + xm;
      bool ok = dIdx < 300;
      const float* wp1 = W1 + (size_t)dIdx * 300 + k0 + xk;
      const float* wp2 = W2 + (size_t)dIdx * 300 + k0 + xk;
#pragma unroll
      for (int j = 0; j < 5; ++j) Ws1[xk + j][xm] = ok ? wp1[j] : 0.f;
#pragma unroll
      for (int j = 0; j < 5; ++j) Ws2[xk + j][xm] = ok ? wp2[j] : 0.f;
    }
    __syncthreads();
#pragma unroll
    for (int kk = 0; kk < 20; ++kk) {
      const float4 a = *(const float4*)&Xs[kk][tm4];
      const float4 w1 = *(const float4*)&Ws1[kk][tn4];
      const float4 w2 = *(const float4*)&Ws2[kk][tn4];
      float av[4] = {a.x, a.y, a.z, a.w};
      float w1v[4] = {w1.x, w1.y, w1.z, w1.w};
      float w2v[4] = {w2.x, w2.y, w2.z, w2.w};
#pragma unroll
      for (int i = 0; i < 4; ++i)
#pragma unroll
        for (int j = 0; j < 4; ++j) {
          acc1[i][j] = fmaf(av[i], w1v[j], acc1[i][j]);
          acc2[i][j] = fmaf(av[i], w2v[j], acc2[i][j]);
        }
    }
    __syncthreads();
  }
#pragma unroll
  for (int i = 0; i < 4; ++i) {
    int row = bm + tm4 + i;
    float* yp = Y + (size_t)row * 300 + n0 + tn4;
#pragma unroll
    for (int j = 0; j < 4; ++j) {
      int col = n0 + tn4 + j;
      if (col < 300) {
        float a = acc1[i][j] + b1[col];
        float b = acc2[i][j] + b2[col];
        yp[j] = (1.f / (1.f + expf(-a))) * tanhf(b);
      }
    }
  }
}

// Batched tiled f32 linear over blockIdx.z: same per-block arithmetic as round 1.
// TRANS: Y[n,d]=sum_k X[n,k]*W[d,k]; !TRANS: Y[n,e]=sum_k X[n,k]*W[k,e].
template <bool TRANS, bool BIAS>
__global__ __launch_bounds__(256)
void linear_kernel(const float* __restrict__ X, const float* __restrict__ W,
                   const float* __restrict__ bias, float* __restrict__ Y,
                   int xz, int wz, int bz, int yz) {
  int z = blockIdx.z;
  X += (size_t)z * xz;
  W += (size_t)z * wz;
  if (BIAS) bias += (size_t)z * bz;
  Y += (size_t)z * yz;
  __shared__ __align__(16) float Xs[20][64];
  __shared__ __align__(16) float Ws_[20][64];
  int t = threadIdx.x;
  int bm = blockIdx.x * 64;
  int n0 = blockIdx.y * 64;
  int tm4 = (t >> 4) * 4;
  int tn4 = (t & 15) * 4;
  float acc[4][4] = {{0.f}};
  int xm = t >> 2;
  int xk = (t & 3) * 5;
  for (int k0 = 0; k0 < 300; k0 += 20) {
    const float* xp = X + (size_t)(bm + xm) * 300 + k0 + xk;
#pragma unroll
    for (int j = 0; j < 5; ++j) Xs[xk + j][xm] = xp[j];
    if (TRANS) {
      int dIdx = n0 + xm;
      bool ok = dIdx < 300;
      const float* wp = W + (size_t)dIdx * 300 + k0 + xk;
#pragma unroll
      for (int j = 0; j < 5; ++j) Ws_[xk + j][xm] = ok ? wp[j] : 0.f;
    } else {
#pragma unroll
      for (int i = 0; i < 5; ++i) {
        int flat = t + i * 256;
        int kk = flat >> 6;
        int nn = flat & 63;
        int col = n0 + nn;
        Ws_[kk][nn] = (col < 300) ? W[(size_t)(k0 + kk) * 300 + col] : 0.f;
      }
    }
    __syncthreads();
#pragma unroll
    for (int kk = 0; kk < 20; ++kk) {
      const float4 a = *(const float4*)&Xs[kk][tm4];
      const float4 w = *(const float4*)&Ws_[kk][tn4];
      float av[4] = {a.x, a.y, a.z, a.w};
      float wv[4] = {w.x, w.y, w.z, w.w};
#pragma unroll
      for (int i = 0; i < 4; ++i)
#pragma unroll
        for (int j = 0; j < 4; ++j)
          acc[i][j] = fmaf(av[i], wv[j], acc[i][j]);
    }
    __syncthreads();
  }
  float bv[4] = {0.f, 0.f, 0.f, 0.f};
  if (BIAS) {
#pragma unroll
    for (int j = 0; j < 4; ++j) {
      int col = n0 + tn4 + j;
      if (col < 300) bv[j] = bias[col];
    }
  }
#pragma unroll
  for (int i = 0; i < 4; ++i) {
    int row = bm + tm4 + i;
    float* yp = Y + (size_t)row * 300 + n0 + tn4;
#pragma unroll
    for (int j = 0; j < 4; ++j) {
      int col = n0 + tn4 + j;
      if (col < 300) yp[j] = acc[i][j] + bv[j];
    }
  }
}

// Review-level scores + gumbel-argmax, batched over z (p). Per-block
// arithmetic identical to round 1 -> identical selections.
__global__ __launch_bounds__(256)
void review_argmax_kernel(const float* __restrict__ Tall, const float* __restrict__ Iall,
                          int* __restrict__ idxU, int* __restrict__ idxI, GKeys K) {
  int b = blockIdx.x, z = blockIdx.y, t = threadIdx.x;
  uint32_t ku0 = K.v[z * 4], ku1 = K.v[z * 4 + 1];
  uint32_t ki0 = K.v[z * 4 + 2], ki1 = K.v[z * 4 + 3];
  __shared__ float Is[9000];
  __shared__ float Sc[900];
  __shared__ float us[30], vs[30];
  const float* Tb = Tall + (size_t)z * 1152000 + (size_t)b * 9000;
  const float* Ib = Iall + (size_t)z * 1152000 + (size_t)b * 9000;
  for (int e = t; e < 9000; e += 256) Is[e] = Ib[e];
  __syncthreads();
  for (int id = t; id < 900; id += 256) {
    int r = id / 30, c = id - r * 30;
    const float* tr = Tb + r * 300;
    const float* ic = Is + c * 300;
    float acc = 0.f;
    for (int k = 0; k < 300; ++k) acc = fmaf(tr[k], ic[k], acc);
    Sc[id] = acc;
  }
  __syncthreads();
  if (t < 30) {
    float m = -3.4e38f;
    for (int c = 0; c < 30; ++c) m = fmaxf(m, Sc[t * 30 + c]);
    us[t] = m + jax_gumbel32(ku0, ku1, (uint32_t)(b * 30 + t));
  } else if (t >= 64 && t < 94) {
    int s = t - 64;
    float m = -3.4e38f;
    for (int r = 0; r < 30; ++r) m = fmaxf(m, Sc[r * 30 + s]);
    vs[s] = m + jax_gumbel32(ki0, ki1, (uint32_t)(b * 30 + s));
  }
  __syncthreads();
  if (t == 0) {
    int best = 0; float bvv = us[0];
    for (int r = 1; r < 30; ++r) { if (us[r] > bvv) { bvv = us[r]; best = r; } }
    idxU[z * 128 + b] = best;
  } else if (t == 1) {
    int best = 0; float bvv = vs[0];
    for (int s = 1; s < 30; ++s) { if (vs[s] > bvv) { bvv = vs[s]; best = s; } }
    idxI[z * 128 + b] = best;
  }
}

// Word-level score-vector chain. zz = p*2 + chain.
// chain 0 (G, user-side scores):  g = Wuw^T ( Mw   (Wiw * mean(WRDi) + biw) )
// chain 1 (H, item-side scores):  h = Wiw^T ( Mw^T (Wuw * mean(WRDu) + buw) )
__global__ __launch_bounds__(320)
void chain_kernel(const int* __restrict__ uRevs, const int* __restrict__ iRevs,
                  const float* __restrict__ uEmb, const float* __restrict__ iEmb,
                  const int* __restrict__ idxU, const int* __restrict__ idxI,
                  const float* __restrict__ Wuw, const float* __restrict__ buw,
                  const float* __restrict__ Wiw, const float* __restrict__ biw,
                  const float* __restrict__ Mw, float* __restrict__ GH) {
  int b = blockIdx.x;
  int zz = blockIdx.y;              // 0..5
  int p = zz >> 1, chain = zz & 1;
  const int* revs = chain ? uRevs : iRevs;
  const float* emb = chain ? uEmb : iEmb;
  int idx = chain ? idxU[p * 128 + b] : idxI[p * 128 + b];
  __shared__ int toks[60];
  __shared__ float A[300], Bv[300];
  int t = threadIdx.x;
  if (t < 60) toks[t] = revs[(b * 30 + idx) * 60 + t];
  __syncthreads();
  if (t < 300) {                    // mean word embedding of selected review
    float acc = 0.f;
    for (int l = 0; l < 60; ++l) acc += emb[(size_t)toks[l] * 300 + t];
    A[t] = acc * (1.f / 60.f);
  }
  __syncthreads();
  int w = t >> 6, j = t & 63;
  // stage1 (row-dot): Bv[e] = sum_k W1[e,k]*A[k] + b1[e]
  const float* W1 = (chain ? Wuw : Wiw) + (size_t)p * 90000;
  const float* b1 = (chain ? buw : biw) + p * 300;
  for (int i = 0; i < 60; ++i) {
    int e = w * 60 + i;
    float partial = 0.f;
#pragma unroll
    for (int c = 0; c < 5; ++c) {
      int k = j + c * 64;
      if (k < 300) partial = fmaf(W1[(size_t)e * 300 + k], A[k], partial);
    }
#pragma unroll
    for (int m = 32; m >= 1; m >>= 1) partial += __shfl_xor(partial, m);
    if (j == 0) Bv[e] = partial + b1[e];
  }
  __syncthreads();
  const float* Mwp = Mw + (size_t)p * 90000;
  if (chain == 0) {                 // A[e] = sum_k Mw[e,k]*Bv[k]
    for (int i = 0; i < 60; ++i) {
      int e = w * 60 + i;
      float partial = 0.f;
#pragma unroll
      for (int c = 0; c < 5; ++c) {
        int k = j + c * 64;
        if (k < 300) partial = fmaf(Mwp[(size_t)e * 300 + k], Bv[k], partial);
      }
#pragma unroll
      for (int m = 32; m >= 1; m >>= 1) partial += __shfl_xor(partial, m);
      if (j == 0) A[e] = partial;
    }
  } else {                          // A[k] = sum_e Mw[e,k]*Bv[e] (coalesced)
    if (t < 300) {
      float acc = 0.f;
      for (int e = 0; e < 300; ++e) acc = fmaf(Mwp[(size_t)e * 300 + t], Bv[e], acc);
      A[t] = acc;
    }
  }
  __syncthreads();
  // stage3: out[k] = sum_e W3[e,k]*A[e] (coalesced)
  const float* W3 = (chain ? Wiw : Wuw) + (size_t)p * 90000;
  if (t < 300) {
    float acc = 0.f;
    for (int e = 0; e < 300; ++e) acc = fmaf(W3[(size_t)e * 300 + t], A[e], acc);
    GH[((size_t)zz * 128 + b) * 300 + t] = acc;
  }
}

// Per (b, side, p): scores = WRD rows . gvec; softmax; weighted sum -> JNT.
__global__ __launch_bounds__(256)
void word_rep_kernel(const int* __restrict__ uRevs, const int* __restrict__ iRevs,
                     const float* __restrict__ uEmb, const float* __restrict__ iEmb,
                     const int* __restrict__ idxU, const int* __restrict__ idxI,
                     const float* __restrict__ GH, float* __restrict__ JNT) {
  int b = blockIdx.x, side = blockIdx.y, p = blockIdx.z;
  const int* revs = side ? iRevs : uRevs;
  const float* emb = side ? iEmb : uEmb;
  int idx = side ? idxI[p * 128 + b] : idxU[p * 128 + b];
  const float* gv = GH + ((size_t)(p * 2 + side) * 128 + b) * 300;
  __shared__ int toks[60];
  __shared__ float g_s[300];
  __shared__ float score[60];
  __shared__ float probs[64];
  int t = threadIdx.x;
  if (t < 60) toks[t] = revs[(b * 30 + idx) * 60 + t];
  for (int d = t; d < 300; d += 256) g_s[d] = gv[d];
  __syncthreads();
  int w = t >> 6, j = t & 63;
  for (int i = 0; i < 15; ++i) {
    int l = w * 15 + i;
    const float* er = emb + (size_t)toks[l] * 300;
    float partial = 0.f;
#pragma unroll
    for (int c = 0; c < 5; ++c) {
      int k = j + c * 64;
      if (k < 300) partial = fmaf(er[k], g_s[k], partial);
    }
#pragma unroll
    for (int m = 32; m >= 1; m >>= 1) partial += __shfl_xor(partial, m);
    if (j == 0) score[l] = partial;
  }
  __syncthreads();
  if (w == 0) {
    float s = (j < 60) ? score[j] : -3.4e38f;
    float m = s;
#pragma unroll
    for (int mm = 32; mm >= 1; mm >>= 1) m = fmaxf(m, __shfl_xor(m, mm));
    float e = (j < 60) ? expf(s - m) : 0.f;
    float sum = e;
#pragma unroll
    for (int mm = 32; mm >= 1; mm >>= 1) sum += __shfl_xor(sum, mm);
    if (j < 60) probs[j] = e / sum;
  }
  __syncthreads();
  float* outp = JNT + (size_t)b * 1800 + side * 900 + p * 300;
  for (int d = t; d < 300; d += 256) {
    float acc = 0.f;
    for (int l = 0; l < 60; ++l)
      acc = fmaf(probs[l], emb[(size_t)toks[l] * 300 + d], acc);
    outp[d] = acc;
  }
}

// Factorization machine (unchanged from round 1).
__global__ __launch_bounds__(64)
void fm_kernel(const float* __restrict__ JNT, const float* __restrict__ w0,
               const float* __restrict__ fw, const float* __restrict__ fv,
               float* __restrict__ out) {
  int b = blockIdx.x, lane = threadIdx.x;
  const float* x = JNT + (size_t)b * 1800;
  float lin = 0.f;
  float t1[10], t2[10];
#pragma unroll
  for (int k = 0; k < 10; ++k) { t1[k] = 0.f; t2[k] = 0.f; }
  for (int j = lane; j < 1800; j += 64) {
    float xv = x[j];
    lin = fmaf(fw[j], xv, lin);
    float xx = xv * xv;
#pragma unroll
    for (int k = 0; k < 10; ++k) {
      float v = fv[j * 10 + k];
      t1[k] = fmaf(xv, v, t1[k]);
      t2[k] = fmaf(xx, v * v, t2[k]);
    }
  }
#pragma unroll
  for (int m = 32; m >= 1; m >>= 1) {
    lin += __shfl_xor(lin, m);
#pragma unroll
    for (int k = 0; k < 10; ++k) {
      t1[k] += __shfl_xor(t1[k], m);
      t2[k] += __shfl_xor(t2[k], m);
    }
  }
  if (lane == 0) {
    float inter = 0.f;
#pragma unroll
    for (int k = 0; k < 10; ++k) inter += t1[k] * t1[k] - t2[k];
    out[b] = w0[0] + lin + 0.5f * inter;
  }
}

extern "C" void kernel_launch(void* const* d_in, const int* in_sizes, int n_in,
                              void* d_out, int out_size, void* d_ws, size_t ws_size,
                              hipStream_t stream) {
  (void)in_sizes; (void)n_in; (void)out_size;
  const int*   uRevs = (const int*)d_in[0];
  const int*   iRevs = (const int*)d_in[1];
  const float* uEmb  = (const float*)d_in[2];
  const float* iEmb  = (const float*)d_in[3];
  const float* g1w   = (const float*)d_in[4];
  const float* g1b   = (const float*)d_in[5];
  const float* g2w   = (const float*)d_in[6];
  const float* g2b   = (const float*)d_in[7];
  const float* Mr    = (const float*)d_in[8];
  const float* Wur   = (const float*)d_in[9];
  const float* bur   = (const float*)d_in[10];
  const float* Wir   = (const float*)d_in[11];
  const float* bir   = (const float*)d_in[12];
  const float* Mw    = (const float*)d_in[13];
  const float* Wuw   = (const float*)d_in[14];
  const float* buw   = (const float*)d_in[15];
  const float* Wiw   = (const float*)d_in[16];
  const float* biw   = (const float*)d_in[17];
  const float* fmw0  = (const float*)d_in[18];
  const float* fmw   = (const float*)d_in[19];
  const float* fmv   = (const float*)d_in[20];
  float* out = (float*)d_out;

  float* ws = (float*)d_ws;
  // Layout (floats):
  //   REV   @ 0          (2,304,000)  [user rows 0.., item rows 3840..]
  //   TPall @ 0          (3,456,000)  [overlays REV after REV is dead]
  //   S     @ 3,456,000  (2,304,000)  [dead after gate]
  //   UPall @ 3,456,000  (3,456,000)  [overlays S]
  //   IPall @ 6,912,000  (3,456,000)
  //   GH    @ 10,368,000 (230,400)
  //   JNT   @ 10,598,400 (230,400)
  //   idx   @ 10,828,800 (768 ints)
  const size_t NEED_BYTES = (size_t)10829568 * 4;
  if (ws_size < NEED_BYTES) return;

  float* REV   = ws + 0;
  float* TPall = ws + 0;
  float* S     = ws + 3456000;
  float* UPall = ws + 3456000;
  float* IPall = ws + 6912000;
  float* GH    = ws + 10368000;
  float* JNT   = ws + 10598400;
  int*   idxU  = (int*)(ws + 10828800);   // [3][128]
  int*   idxI  = idxU + 384;

  // Phase 1: gather-sum + fused review gate
  gather_sum_kernel<<<dim3(7680), dim3(320), 0, stream>>>(uRevs, iRevs, uEmb, iEmb, S);
  gate_fused_kernel<<<dim3(120, 5), 256, 0, stream>>>(S, g1w, g1b, g2w, g2b, REV);

  // Phase 2: review-level co-attention (z-batched over p) + gumbel-argmax
  {
    dim3 g(60, 5, 3);
    linear_kernel<true, true><<<g, 256, 0, stream>>>(
        REV, Wur, bur, UPall, 0, 90000, 300, 1152000);
    linear_kernel<true, true><<<g, 256, 0, stream>>>(
        REV + (size_t)3840 * 300, Wir, bir, IPall, 0, 90000, 300, 1152000);
    linear_kernel<false, false><<<g, 256, 0, stream>>>(
        UPall, Mr, nullptr, TPall, 1152000, 90000, 0, 1152000);
    GKeys K;
    for (int p = 0; p < 3; ++p) {
      tf2x32(0u, 42u, 0u, (uint32_t)(2 * p),     &K.v[p * 4],     &K.v[p * 4 + 1]);
      tf2x32(0u, 42u, 0u, (uint32_t)(2 * p + 1), &K.v[p * 4 + 2], &K.v[p * 4 + 3]);
    }
    review_argmax_kernel<<<dim3(128, 3), 256, 0, stream>>>(TPall, IPall, idxU, idxI, K);
  }

  // Phase 3: factorized word-level co-attention
  chain_kernel<<<dim3(128, 6), 320, 0, stream>>>(
      uRevs, iRevs, uEmb, iEmb, idxU, idxI, Wuw, buw, Wiw, biw, Mw, GH);
  word_rep_kernel<<<dim3(128, 2, 3), 256, 0, stream>>>(
      uRevs, iRevs, uEmb, iEmb, idxU, idxI, GH, JNT);

  // Phase 4: factorization machine
  fm_kernel<<<dim3(128), 64, 0, stream>>>(JNT, fmw0, fmw, fmv, out);
}